// Round 9
// baseline (270.427 us; speedup 1.0000x reference)
//
#include <hip/hip_runtime.h>
#include <math.h>

// DTW 2048x2048, squared-diff cost, out = sqrt(DTW[2047][2047]).
//
// Round-9: kill the per-column conveyor overhead. Model from R5-R8:
// wall = waves/SIMD * steps * I * 2cy * sf, sf~2.0 caused by readlane/DPP
// hazard stalls in the per-column delivery. New structure: C=4 cols/body,
// all cross-lane & LDS inputs have >= 1 full body (~230cy) of lead.
//
// NW=4 waves (256 thr), R=8 rows/lane, lane skew = 1 body = 4 cols.
// Lane l of wave w owns rows 8*(64w+l)..+7; body tau computes cols
// c0=4(tau-l) .. c0+3 (32 cells, col-serial x row-serial, min3+fma).
//
// Up-row delivery: lane l-1's bottom-row 4 cols for body tau are exactly
// its PREVIOUS body's bot4 registers -> 4 v_mov_dpp (wave_shr:1), sources
// written ~230cy ago (no wait-states, no readlane). Lane 0 takes the DPP
// 'old' operand = ring values from a wave-uniform broadcast ds_read_b128,
// prefetched one body ahead (producer wrote them >=1 barrier earlier).
// y: per-lane ds_read_b128 (4 cols), prefetched one body ahead, padded yS.
// Diag for (row0, c0) = previous body's u3 (register carry; tid0 seeds 0).
//
// Bottom-row write: one all-lane ds_write_b128; lane 63 -> ring row w+1
// (wrapped 256 cols), lanes 0-62 -> private 80B garbage slots (sharing the
// ring row is unsafe: lane-0's wrap revisit lands 16 steps BEFORE the
// consumer's read). Ring timing (SK=80, CSTEP=16): producer lane63 writes
// col c at body c/4+63, wall (c/4+63+80w); consumer (wave w+1) prefetches
// at wall (c/4-1+80w+80) -> gap 16 = one full block -> barrier between.
//
// Guard-free INFV: ramp cells are exactly INFV (1e30+d^2==1e30, min
// filters NaN), OOB-col garbage confined (DP flows right/down). Output at
// w=3, lane=63, body 574 (block tau0=560, s=14, col k=3 -> 2047).
//
// LDS (floats): ring [0,1280) 5 rows x 256 (row0=INF, wave w writes row
// w+1, reads row w); garbage [1280,2540) 63x20; yPad [2560,5120), y at
// +252 so body/prefetch indices 2812+4*(tau-l) stay in-bounds for
// tau in [-63, 576].

#define NLEN  2048
#define NW    4
#define CSTEP 16
#define SK    80
#define GTOT  816
#define TAU_LAST 560
#define INFV  1e30f

__device__ __forceinline__ float dpp_shr1(float v, float inj) {
    int r = __builtin_amdgcn_update_dpp(
        __builtin_bit_cast(int, inj), __builtin_bit_cast(int, v),
        0x138 /*wave_shr:1*/, 0xF, 0xF, false /*lane0 takes old=inj*/);
    return __builtin_bit_cast(float, r);
}

// One column of 8 rows: returns bottom-row value, updates v[] in place.
__device__ __forceinline__ float docol(float yk, float uk, float dgk,
                                       float* v, const float* x) {
    float up = uk, dg = dgk;
    #pragma unroll
    for (int r = 0; r < 8; ++r) {
        float d  = x[r] - yk;
        float nn = fmaf(d, d, fminf(fminf(v[r], dg), up));
        dg = v[r]; v[r] = nn; up = nn;
    }
    return up;
}

__global__ __launch_bounds__(256, 1) void dtw_kernel(const float* __restrict__ X,
                                                     const float* __restrict__ Y,
                                                     float* __restrict__ out) {
    __shared__ __align__(16) float ldsF[5120];

    const int tid  = threadIdx.x;
    const int w    = tid >> 6;
    const int lane = tid & 63;

    // ---- prologue: stage y (at float offset 2812), pads, ring=INF ----
    {
        float4* dst = (float4*)&ldsF[2812];
        const float4* src = (const float4*)Y;
        dst[tid]       = src[tid];
        dst[tid + 256] = src[tid + 256];
    }
    if (tid < 252) ldsF[2560 + tid] = 0.0f;          // low pad
    { int k = tid; if (k < 260) ldsF[4860 + k] = 0.0f; }  // high pad
    for (int k = tid; k < 1280; k += 256) ldsF[k] = INFV; // ring rows
    __syncthreads();

    float x[8];
    {
        const float4 xa = *(const float4*)&X[tid * 8];
        const float4 xb = *(const float4*)&X[tid * 8 + 4];
        x[0] = xa.x; x[1] = xa.y; x[2] = xa.z; x[3] = xa.w;
        x[4] = xb.x; x[5] = xb.y; x[6] = xb.z; x[7] = xb.w;
    }

    float v[8];
    #pragma unroll
    for (int r = 0; r < 8; ++r) v[r] = INFV;
    float  carry = (tid == 0) ? 0.0f : INFV;   // diag seed DTW[-1][-1]=0
    float4 botp  = make_float4(INFV, INFV, INFV, INFV);
    float4 rg    = botp, yc = botp;            // cur prefetch regs

    // Address state (float indices).
    const int rBase = w * 256;                 // ring row w (read)
    int rOff = 0;                              // slot (4*tau)&255
    int yIdx = 2812 - 4 * lane;                // body-0 y position
    const int wBase = (lane == 63) ? (w + 1) * 256 : 1280 + 20 * lane;
    const int wMask = (lane == 63) ? 255 : 15;
    int wOff = (-4 * lane) & wMask;            // body-0 write slot

    for (int gb = 0; gb < GTOT; gb += CSTEP) {
        const int tau0 = gb - w * SK;

        if (tau0 >= 0 && tau0 <= TAU_LAST) {
            if (tau0 == 0) {   // first active block: load body-0 data
                rg = *(const float4*)&ldsF[rBase + rOff];
                yc = *(const float4*)&ldsF[yIdx];
            }
            const bool isout = (tau0 == TAU_LAST) & (w == NW - 1) & (lane == 63);

            #pragma unroll
            for (int s = 0; s < CSTEP; ++s) {
                // prefetch for body tau+1 (data >= 1 body old by design)
                rOff = (rOff + 4) & 255;
                const float4 rgn = *(const float4*)&ldsF[rBase + rOff];
                yIdx += 4;
                const float4 yn = *(const float4*)&ldsF[yIdx];
                // up-row: lane l-1's previous-body bottom row (lane0: ring)
                const float u0 = dpp_shr1(botp.x, rg.x);
                const float u1 = dpp_shr1(botp.y, rg.y);
                const float u2 = dpp_shr1(botp.z, rg.z);
                const float u3 = dpp_shr1(botp.w, rg.w);
                // 4 columns x 8 rows
                const float b0 = docol(yc.x, u0, carry, v, x);
                const float b1 = docol(yc.y, u1, u0, v, x);
                const float b2 = docol(yc.z, u2, u1, v, x);
                const float b3 = docol(yc.w, u3, u2, v, x);
                // bottom-row 4 cols -> ring (lane63) / garbage (others)
                *(float4*)&ldsF[wBase + wOff] = make_float4(b0, b1, b2, b3);
                wOff = (wOff + 4) & wMask;
                // rotate state
                botp  = make_float4(b0, b1, b2, b3);
                carry = u3;
                rg = rgn; yc = yn;
                if (s == 14 && isout) out[0] = sqrtf(b3);   // col 2047
            }
        }
        __syncthreads();
    }
}

extern "C" void kernel_launch(void* const* d_in, const int* in_sizes, int n_in,
                              void* d_out, int out_size, void* d_ws, size_t ws_size,
                              hipStream_t stream) {
    const float* x = (const float*)d_in[0];
    const float* y = (const float*)d_in[1];
    (void)in_sizes; (void)n_in; (void)out_size; (void)d_ws; (void)ws_size;
    dtw_kernel<<<1, 256, 0, stream>>>(x, y, (float*)d_out);
}

// Round 10
// 264.020 us; speedup vs baseline: 1.0243x; 1.0243x over previous
//
#include <hip/hip_runtime.h>
#include <math.h>

// DTW 2048x2048, squared-diff cost, out = sqrt(DTW[2047][2047]).
//
// Round-10 = Round-9 structure with ONE fix: the bottom-row ring write is
// lane-63-only (exec-masked ds_write_b128). R9's all-lane write scattered
// b128s across 20-float-strided garbage slots -> 8-way bank conflicts
// (SQ_LDS_BANK_CONFLICT=331872 ~ 138us of the 222us). Lanes 0-62's data
// was never read; removing the writes is free.
//
// Structure (R9, validated absmax 0.0): NW=4 waves (256 thr), R=8 rows/lane,
// C=4 cols/body, lane skew = 1 body. Lane l of wave w owns rows
// 8*(64w+l)..+7; body tau computes cols 4(tau-l)..+3 (32 cells).
// Up-row: lane l-1's previous-body bottom-row regs via 4 v_mov_dpp
// (wave_shr:1, sources ~1 body old -> no hazard stalls); lane 0 takes the
// DPP 'old' operand = ring values from a wave-uniform broadcast
// ds_read_b128 prefetched one body ahead. y: per-lane ds_read_b128
// (contiguous across lanes), prefetched one body ahead, padded yS.
// Diag carry = previous body's u3 (tid0 seeds DTW[-1][-1]=0).
//
// Ring timing (SK=80, CSTEP=16): producer lane63 writes col c at body
// c/4+63 (wall c/4+63+80w); consumer wave w+1 prefetches it at wall
// c/4+79+80w -> one full block + barrier in between. Wrap (256 slots):
// slot reuse is >=1 full ring period later; ramp writes (cols<0, INFV)
// precede all real writes of the same single writer lane.
//
// Guard-free INFV: ramp cells stay exactly INFV (1e30+d^2==1e30 in fp32);
// OOB-col garbage confined (DP flows right/down only). Output at w=3,
// lane=63, block tau0=560, s=14 (col 2047).
//
// LDS (floats): ring [0,1280) 5 rows x 256 (row0=INF; wave w reads row w,
// writes row w+1); yPad [2560,5120) with y data at +2812 so indices
// 2812+4*(tau-l) stay in-bounds for tau in [-63,576].

#define NLEN  2048
#define NW    4
#define CSTEP 16
#define SK    80
#define GTOT  816
#define TAU_LAST 560
#define INFV  1e30f

__device__ __forceinline__ float dpp_shr1(float v, float inj) {
    int r = __builtin_amdgcn_update_dpp(
        __builtin_bit_cast(int, inj), __builtin_bit_cast(int, v),
        0x138 /*wave_shr:1*/, 0xF, 0xF, false /*lane0 takes old=inj*/);
    return __builtin_bit_cast(float, r);
}

// One column of 8 rows: returns bottom-row value, updates v[] in place.
__device__ __forceinline__ float docol(float yk, float uk, float dgk,
                                       float* v, const float* x) {
    float up = uk, dg = dgk;
    #pragma unroll
    for (int r = 0; r < 8; ++r) {
        float d  = x[r] - yk;
        float nn = fmaf(d, d, fminf(fminf(v[r], dg), up));
        dg = v[r]; v[r] = nn; up = nn;
    }
    return up;
}

__global__ __launch_bounds__(256, 1) void dtw_kernel(const float* __restrict__ X,
                                                     const float* __restrict__ Y,
                                                     float* __restrict__ out) {
    __shared__ __align__(16) float ldsF[5120];

    const int tid  = threadIdx.x;
    const int w    = tid >> 6;
    const int lane = tid & 63;

    // ---- prologue: stage y (float offset 2812), pads, ring=INF ----
    {
        float4* dst = (float4*)&ldsF[2812];
        const float4* src = (const float4*)Y;
        dst[tid]       = src[tid];
        dst[tid + 256] = src[tid + 256];
    }
    if (tid < 252) ldsF[2560 + tid] = 0.0f;               // low pad
    { int k = tid; if (k < 260) ldsF[4860 + k] = 0.0f; }  // high pad
    for (int k = tid; k < 1280; k += 256) ldsF[k] = INFV; // ring rows
    __syncthreads();

    float x[8];
    {
        const float4 xa = *(const float4*)&X[tid * 8];
        const float4 xb = *(const float4*)&X[tid * 8 + 4];
        x[0] = xa.x; x[1] = xa.y; x[2] = xa.z; x[3] = xa.w;
        x[4] = xb.x; x[5] = xb.y; x[6] = xb.z; x[7] = xb.w;
    }

    float v[8];
    #pragma unroll
    for (int r = 0; r < 8; ++r) v[r] = INFV;
    float  carry = (tid == 0) ? 0.0f : INFV;   // diag seed DTW[-1][-1]=0
    float4 botp  = make_float4(INFV, INFV, INFV, INFV);
    float4 rg    = botp, yc = botp;

    const int rBase = w * 256;                 // ring row w (read)
    int rOff = 0;
    int yIdx = 2812 - 4 * lane;                // body-0 y position
    const int wBase = (w + 1) * 256;           // ring row w+1 (write, lane63)
    int wOff = (-4 * lane) & 255;              // only lane 63's value used
    const bool writer = (lane == 63);

    for (int gb = 0; gb < GTOT; gb += CSTEP) {
        const int tau0 = gb - w * SK;

        if (tau0 >= 0 && tau0 <= TAU_LAST) {
            if (tau0 == 0) {   // first active block: load body-0 data
                rg = *(const float4*)&ldsF[rBase + rOff];
                yc = *(const float4*)&ldsF[yIdx];
            }
            const bool isout = (tau0 == TAU_LAST) & (w == NW - 1) & writer;

            #pragma unroll
            for (int s = 0; s < CSTEP; ++s) {
                // prefetch body tau+1 inputs (data >= 1 barrier old)
                rOff = (rOff + 4) & 255;
                const float4 rgn = *(const float4*)&ldsF[rBase + rOff];
                yIdx += 4;
                const float4 yn = *(const float4*)&ldsF[yIdx];
                // up-row: lane l-1's previous-body bottom row (lane0: ring)
                const float u0 = dpp_shr1(botp.x, rg.x);
                const float u1 = dpp_shr1(botp.y, rg.y);
                const float u2 = dpp_shr1(botp.z, rg.z);
                const float u3 = dpp_shr1(botp.w, rg.w);
                // 4 columns x 8 rows
                const float b0 = docol(yc.x, u0, carry, v, x);
                const float b1 = docol(yc.y, u1, u0, v, x);
                const float b2 = docol(yc.z, u2, u1, v, x);
                const float b3 = docol(yc.w, u3, u2, v, x);
                // bottom-row 4 cols -> ring: lane 63 ONLY (conflict-free)
                if (writer)
                    *(float4*)&ldsF[wBase + wOff] = make_float4(b0, b1, b2, b3);
                wOff = (wOff + 4) & 255;
                // rotate state
                botp  = make_float4(b0, b1, b2, b3);
                carry = u3;
                rg = rgn; yc = yn;
                if (s == 14 && isout) out[0] = sqrtf(b3);   // col 2047
            }
        }
        __syncthreads();
    }
}

extern "C" void kernel_launch(void* const* d_in, const int* in_sizes, int n_in,
                              void* d_out, int out_size, void* d_ws, size_t ws_size,
                              hipStream_t stream) {
    const float* x = (const float*)d_in[0];
    const float* y = (const float*)d_in[1];
    (void)in_sizes; (void)n_in; (void)out_size; (void)d_ws; (void)ws_size;
    dtw_kernel<<<1, 256, 0, stream>>>(x, y, (float*)d_out);
}